// Round 4
// baseline (28159.540 us; speedup 1.0000x reference)
//
#include <hip/hip_runtime.h>

// Model: B=32, L1=512, L2=16, D=300, H=300, V=50000, C=3
#define B_  32
#define L1_ 512
#define L2_ 16
#define D_  300
#define H_  300

__device__ __forceinline__ float sigmoid_fast(float x) {
    return 1.0f / (1.0f + __expf(-x));
}
__device__ __forceinline__ float tanh_fast(float x) {
    x = fminf(fmaxf(x, -15.0f), 15.0f);
    float e = __expf(2.0f * x);
    return (e - 1.0f) / (e + 1.0f);
}
// accurate versions for the GRU recurrence (error accumulates over 512 steps)
__device__ __forceinline__ float sigmoid_acc(float x) {
    return 1.0f / (1.0f + expf(-x));
}
__device__ __forceinline__ float wred_sum(float v) {
    #pragma unroll
    for (int off = 32; off > 0; off >>= 1) v += __shfl_xor(v, off);
    return v;
}
__device__ __forceinline__ float wred_max(float v) {
    #pragma unroll
    for (int off = 32; off > 0; off >>= 1) v = fmaxf(v, __shfl_xor(v, off));
    return v;
}

// ---------------- gather rows of emb (row length 300 = 75 float4) ----------------
__global__ __launch_bounds__(256) void gather_kernel(const float* __restrict__ emb,
                                                     const int* __restrict__ ids,
                                                     float* __restrict__ out, int total) {
    for (int i = blockIdx.x * 256 + threadIdx.x; i < total; i += gridDim.x * 256) {
        int row = i / 75, c = i % 75;
        int id = ids[row];
        reinterpret_cast<float4*>(out)[i] =
            reinterpret_cast<const float4*>(emb + (size_t)id * 300)[c];
    }
}

// ---------------- fp32 GEMM: C[M,N] = A[M,K] @ W[N,K]^T (+ bias[n]) ----------------
#define TM 128
#define TN 64
#define TK 16
__global__ __launch_bounds__(256) void gemm_nt(const float* __restrict__ A,
                                               const float* __restrict__ W,
                                               const float* __restrict__ bias,
                                               float* __restrict__ C,
                                               int M, int N, int K) {
    __shared__ __align__(16) float As[TK][TM + 4];
    __shared__ __align__(16) float Bs[TK][TN + 4];
    const int tid = threadIdx.x;
    const int m0 = blockIdx.x * TM;
    const int n0 = blockIdx.y * TN;
    const int tx = tid & 15;
    const int ty = tid >> 4;
    const int lr = tid >> 2;
    const int lk = (tid & 3) << 2;

    float acc[8][4];
    #pragma unroll
    for (int i = 0; i < 8; ++i)
        #pragma unroll
        for (int j = 0; j < 4; ++j) acc[i][j] = 0.f;

    for (int k0 = 0; k0 < K; k0 += TK) {
        const bool kok = (k0 + lk + 3) < K;
        #pragma unroll
        for (int h = 0; h < 2; ++h) {
            float4 v = make_float4(0.f, 0.f, 0.f, 0.f);
            int m = m0 + lr + 64 * h;
            if (kok) v = *reinterpret_cast<const float4*>(&A[(size_t)m * K + k0 + lk]);
            As[lk + 0][lr + 64 * h] = v.x;
            As[lk + 1][lr + 64 * h] = v.y;
            As[lk + 2][lr + 64 * h] = v.z;
            As[lk + 3][lr + 64 * h] = v.w;
        }
        {
            float4 v = make_float4(0.f, 0.f, 0.f, 0.f);
            int n = n0 + lr;
            if (kok && n < N) v = *reinterpret_cast<const float4*>(&W[(size_t)n * K + k0 + lk]);
            Bs[lk + 0][lr] = v.x;
            Bs[lk + 1][lr] = v.y;
            Bs[lk + 2][lr] = v.z;
            Bs[lk + 3][lr] = v.w;
        }
        __syncthreads();
        #pragma unroll
        for (int k = 0; k < TK; ++k) {
            float4 a0 = *reinterpret_cast<const float4*>(&As[k][ty * 8]);
            float4 a1 = *reinterpret_cast<const float4*>(&As[k][ty * 8 + 4]);
            float4 bv = *reinterpret_cast<const float4*>(&Bs[k][tx * 4]);
            float av[8] = {a0.x, a0.y, a0.z, a0.w, a1.x, a1.y, a1.z, a1.w};
            float bb[4] = {bv.x, bv.y, bv.z, bv.w};
            #pragma unroll
            for (int i = 0; i < 8; ++i)
                #pragma unroll
                for (int j = 0; j < 4; ++j) acc[i][j] += av[i] * bb[j];
        }
        __syncthreads();
    }
    #pragma unroll
    for (int i = 0; i < 8; ++i) {
        int m = m0 + ty * 8 + i;
        #pragma unroll
        for (int j = 0; j < 4; ++j) {
            int n = n0 + tx * 4 + j;
            if (n < N) C[(size_t)m * N + n] = acc[i][j] + (bias ? bias[n] : 0.f);
        }
    }
}

// ---------------- attention: scores -> alpha -> context_ -> beta logits ----------------
__global__ __launch_bounds__(256) void attn_kernel(const float* __restrict__ c_proj,
                                                   const float* __restrict__ a_proj,
                                                   const float* __restrict__ asp_emb,
                                                   const float* __restrict__ lin,
                                                   const float* __restrict__ Vatt,
                                                   const float* __restrict__ Vw,
                                                   const float* __restrict__ bVw,
                                                   float* __restrict__ blogit) {
    const int b = blockIdx.y;
    const int chunk = blockIdx.x;
    __shared__ float sA[16 * 300];
    __shared__ float sE[16 * 300];
    __shared__ float sV[300];
    __shared__ float sW[300];
    const int tid = threadIdx.x;
    for (int i = tid; i < 16 * 300; i += 256) {
        sA[i] = a_proj[b * 4800 + i];
        sE[i] = asp_emb[b * 4800 + i];
    }
    for (int i = tid; i < 300; i += 256) {
        sV[i] = Vatt[i];
        sW[i] = Vw[i];
    }
    __syncthreads();
    const int wave = tid >> 6, lane = tid & 63;
    const float bvw = bVw[0];
    for (int li = 0; li < 4; ++li) {
        const int l = chunk * 16 + wave * 4 + li;
        const float* crow = c_proj + (size_t)(b * L1_ + l) * 300;
        float cr[5];
        #pragma unroll
        for (int i = 0; i < 5; ++i) {
            int d = lane + 64 * i;
            cr[i] = (d < 300) ? crow[d] : 0.f;
        }
        float sc[16];
        #pragma unroll
        for (int m = 0; m < 16; ++m) {
            float s = 0.f;
            #pragma unroll
            for (int i = 0; i < 5; ++i) {
                int d = lane + 64 * i;
                if (d < 300) s += tanh_fast(cr[i] + sA[m * 300 + d]) * sV[d];
            }
            s = wred_sum(s);
            sc[m] = s;
        }
        float mx = sc[0];
        #pragma unroll
        for (int m = 1; m < 16; ++m) mx = fmaxf(mx, sc[m]);
        float den = 0.f;
        #pragma unroll
        for (int m = 0; m < 16; ++m) {
            sc[m] = __expf(sc[m] - mx);
            den += sc[m];
        }
        const float inv = 1.f / den;
        const float* lrow = lin + (size_t)(b * L1_ + l) * 300;
        float acc = 0.f;
        #pragma unroll
        for (int i = 0; i < 5; ++i) {
            int d = lane + 64 * i;
            if (d < 300) {
                float cd = 0.f;
                #pragma unroll
                for (int m = 0; m < 16; ++m) cd += sc[m] * sE[m * 300 + d];
                acc += tanh_fast(lrow[d] + cd * inv) * sW[d];
            }
        }
        acc = wred_sum(acc);
        if (lane == 0) blogit[b * L1_ + l] = acc + bvw;
    }
}

// ---------------- beta softmax over L1=512 per batch ----------------
__global__ __launch_bounds__(256) void beta_softmax_kernel(const float* __restrict__ x,
                                                           float* __restrict__ y) {
    const int b = blockIdx.x, tid = threadIdx.x;
    __shared__ float red[4];
    const int wave = tid >> 6, lane = tid & 63;
    float v0 = x[b * 512 + tid];
    float v1 = x[b * 512 + 256 + tid];
    float m = wred_max(fmaxf(v0, v1));
    if (lane == 0) red[wave] = m;
    __syncthreads();
    m = fmaxf(fmaxf(red[0], red[1]), fmaxf(red[2], red[3]));
    float e0 = __expf(v0 - m), e1 = __expf(v1 - m);
    float s = wred_sum(e0 + e1);
    __syncthreads();
    if (lane == 0) red[wave] = s;
    __syncthreads();
    s = red[0] + red[1] + red[2] + red[3];
    const float inv = 1.f / s;
    y[b * 512 + tid] = e0 * inv;
    y[b * 512 + 256 + tid] = e1 * inv;
}

// ---------------- GRU v4: one 1024-thread WG per (batch, direction) ----------------
// No cross-WG communication at all. Thread (q = tid>>8, rb = tid&255) owns the
// 76-wide k-slice [76q, 76q+76) of rows {rb + 256j, j<4, row<900} -> 304 weight
// floats pinned in VGPRs. Per step: read h-slice from LDS (19 ds_read_b128),
// 4 partial dot products, LDS reduce across the 4 k-slices (+bhh), 300 threads
// do the gate update. Gates use accurate expf/tanhf (300 threads: free).
__global__ __launch_bounds__(1024, 4) void gru4_kernel(const float* __restrict__ xg_f,
                                                       const float* __restrict__ xg_b,
                                                       const float* __restrict__ whh_f,
                                                       const float* __restrict__ whh_b,
                                                       const float* __restrict__ bhh_f,
                                                       const float* __restrict__ bhh_b,
                                                       const float* __restrict__ beta,
                                                       float* __restrict__ senti) {
    const int g = blockIdx.x;       // 0..63
    const int b = g & 31;
    const int rev = g >> 5;
    const float* xg  = rev ? xg_b : xg_f;
    const float* whh = rev ? whh_b : whh_f;
    const float* bhh = rev ? bhh_b : bhh_f;

    const int tid = threadIdx.x;
    const int q = tid >> 8;         // k-slice 0..3 (start 76q)
    const int rb = tid & 255;       // row base

    __shared__ __align__(16) float hs[304];     // h, zero-padded to 304
    __shared__ float part[4][1024];             // partial sums, [q][row]
    __shared__ float gg[904];                   // reduced gate pre-activations

    // ---- weights -> registers (guarded, OOB-safe), then asm-pinned ----
    float4 w[4][19];
    #pragma unroll
    for (int j = 0; j < 4; ++j)
        #pragma unroll
        for (int k = 0; k < 19; ++k) w[j][k] = make_float4(0.f, 0.f, 0.f, 0.f);
    #pragma unroll
    for (int j = 0; j < 4; ++j) {
        const int r = rb + 256 * j;
        if (r < 900) {
            const float4* wp = reinterpret_cast<const float4*>(whh + (size_t)r * 300 + 76 * q);
            #pragma unroll
            for (int k = 0; k < 18; ++k) w[j][k] = wp[k];
            // k=18 covers floats 72..75 of the slice; for q==3 those are cols
            // 300..303 (past row end). Clamp the address and zero the value.
            float4 v18 = wp[(q == 3) ? 0 : 18];
            w[j][18] = (q == 3) ? make_float4(0.f, 0.f, 0.f, 0.f) : v18;
        }
    }
    #pragma unroll
    for (int j = 0; j < 4; ++j)
        #pragma unroll
        for (int k = 0; k < 19; ++k)
            asm volatile("" : "+v"(w[j][k].x), "+v"(w[j][k].y), "+v"(w[j][k].z), "+v"(w[j][k].w));

    const float bhr = (tid < 900) ? bhh[tid] : 0.f;

    for (int i = tid; i < 304; i += 1024) hs[i] = 0.f;
    float sacc = 0.f;
    __syncthreads();

    const float4* hsq = reinterpret_cast<const float4*>(hs) + 19 * q;
    for (int step = 0; step < 512; ++step) {
        const int t = rev ? (511 - step) : step;
        // prefetch xg/beta (independent of h; latency hides under the matvec)
        float xr = 0.f, xz = 0.f, xn = 0.f, bt = 0.f;
        if (tid < 300) {
            const float* xrow = xg + (size_t)(b * 512 + t) * 900;
            xr = xrow[tid];
            xz = xrow[300 + tid];
            xn = xrow[600 + tid];
            bt = beta[b * 512 + t];
        }
        // 4 independent partial dot products from pinned registers
        float a0 = 0.f, a1 = 0.f, a2 = 0.f, a3 = 0.f;
        #pragma unroll
        for (int k = 0; k < 19; ++k) {
            const float4 hv = hsq[k];
            a0 = fmaf(w[0][k].x, hv.x, a0); a0 = fmaf(w[0][k].y, hv.y, a0);
            a0 = fmaf(w[0][k].z, hv.z, a0); a0 = fmaf(w[0][k].w, hv.w, a0);
            a1 = fmaf(w[1][k].x, hv.x, a1); a1 = fmaf(w[1][k].y, hv.y, a1);
            a1 = fmaf(w[1][k].z, hv.z, a1); a1 = fmaf(w[1][k].w, hv.w, a1);
            a2 = fmaf(w[2][k].x, hv.x, a2); a2 = fmaf(w[2][k].y, hv.y, a2);
            a2 = fmaf(w[2][k].z, hv.z, a2); a2 = fmaf(w[2][k].w, hv.w, a2);
            a3 = fmaf(w[3][k].x, hv.x, a3); a3 = fmaf(w[3][k].y, hv.y, a3);
            a3 = fmaf(w[3][k].z, hv.z, a3); a3 = fmaf(w[3][k].w, hv.w, a3);
        }
        part[q][rb]       = a0;   // rows >= 900 land in part[q][900..1023]: unused
        part[q][rb + 256] = a1;
        part[q][rb + 512] = a2;
        part[q][rb + 768] = a3;
        __syncthreads();
        if (tid < 900)
            gg[tid] = bhr + part[0][tid] + part[1][tid] + part[2][tid] + part[3][tid];
        __syncthreads();
        if (tid < 300) {
            const float rr = sigmoid_acc(xr + gg[tid]);
            const float zz = sigmoid_acc(xz + gg[300 + tid]);
            const float nn = tanhf(xn + rr * gg[600 + tid]);
            const float hn = (1.f - zz) * nn + zz * hs[tid];
            sacc = fmaf(bt, hn, sacc);
            hs[tid] = hn;
        }
        __syncthreads();
    }
    if (tid < 300) senti[b * 600 + rev * 300 + tid] = sacc;
}

// ---------------- final logits: (32,600) x (3,600)^T + outb ----------------
__global__ __launch_bounds__(64) void logits_kernel(const float* __restrict__ senti,
                                                    const float* __restrict__ outW,
                                                    const float* __restrict__ outb,
                                                    float* __restrict__ out) {
    const int b = blockIdx.x, lane = threadIdx.x;
    for (int c = 0; c < 3; ++c) {
        float s = 0.f;
        for (int hh = lane; hh < 600; hh += 64) s += senti[b * 600 + hh] * outW[c * 600 + hh];
        s = wred_sum(s);
        if (lane == 0) out[b * 3 + c] = s + outb[c];
    }
}

extern "C" void kernel_launch(void* const* d_in, const int* in_sizes, int n_in,
                              void* d_out, int out_size, void* d_ws, size_t ws_size,
                              hipStream_t stream) {
    const int* ctx_ids = (const int*)d_in[0];
    const int* asp_ids = (const int*)d_in[1];
    // d_in[2], d_in[3]: masks (all ones, unused by reference)
    const float* emb   = (const float*)d_in[4];
    const float* Wc    = (const float*)d_in[5];
    const float* Wa    = (const float*)d_in[6];
    const float* Vatt  = (const float*)d_in[7];
    const float* Wlin  = (const float*)d_in[8];
    const float* blin  = (const float*)d_in[9];
    const float* Vw    = (const float*)d_in[10];
    const float* bVw   = (const float*)d_in[11];
    const float* wih_f = (const float*)d_in[12];
    const float* whh_f = (const float*)d_in[13];
    const float* bih_f = (const float*)d_in[14];
    const float* bhh_f = (const float*)d_in[15];
    const float* wih_b = (const float*)d_in[16];
    const float* whh_b = (const float*)d_in[17];
    const float* bih_b = (const float*)d_in[18];
    const float* bhh_b = (const float*)d_in[19];
    const float* outW  = (const float*)d_in[20];
    const float* outb  = (const float*)d_in[21];
    float* ws = (float*)d_ws;

    size_t o = 0;
    float* ctx_emb = ws + o; o += (size_t)B_ * L1_ * D_;
    float* asp_emb = ws + o; o += (size_t)B_ * L2_ * D_;
    float* c_proj  = ws + o; o += (size_t)B_ * L1_ * D_;
    float* a_proj  = ws + o; o += (size_t)B_ * L2_ * D_;
    float* lin_buf = ws + o; o += (size_t)B_ * L1_ * D_;
    float* xg_f    = ws + o; o += (size_t)B_ * L1_ * 3 * H_;
    float* xg_b    = ws + o; o += (size_t)B_ * L1_ * 3 * H_;
    float* blogit  = ws + o; o += (size_t)B_ * L1_;
    float* beta    = ws + o; o += (size_t)B_ * L1_;
    float* senti   = ws + o; o += (size_t)B_ * 2 * H_;

    dim3 blk(256);
    const int tot_ctx = B_ * L1_ * 75;
    const int tot_asp = B_ * L2_ * 75;
    gather_kernel<<<dim3((tot_ctx + 255) / 256), blk, 0, stream>>>(emb, ctx_ids, ctx_emb, tot_ctx);
    gather_kernel<<<dim3((tot_asp + 255) / 256), blk, 0, stream>>>(emb, asp_ids, asp_emb, tot_asp);

    gemm_nt<<<dim3(16384 / 128, 5), blk, 0, stream>>>(ctx_emb, Wc, nullptr, c_proj, 16384, 300, 300);
    gemm_nt<<<dim3(16384 / 128, 5), blk, 0, stream>>>(ctx_emb, Wlin, blin, lin_buf, 16384, 300, 300);
    gemm_nt<<<dim3(512 / 128, 5), blk, 0, stream>>>(asp_emb, Wa, nullptr, a_proj, 512, 300, 300);
    gemm_nt<<<dim3(16384 / 128, 15), blk, 0, stream>>>(ctx_emb, wih_f, bih_f, xg_f, 16384, 900, 300);
    gemm_nt<<<dim3(16384 / 128, 15), blk, 0, stream>>>(ctx_emb, wih_b, bih_b, xg_b, 16384, 900, 300);

    attn_kernel<<<dim3(32, 32), blk, 0, stream>>>(c_proj, a_proj, asp_emb, lin_buf, Vatt, Vw, bVw, blogit);
    beta_softmax_kernel<<<dim3(32), blk, 0, stream>>>(blogit, beta);
    gru4_kernel<<<dim3(64), dim3(1024), 0, stream>>>(xg_f, xg_b, whh_f, whh_b, bhh_f, bhh_b,
                                                     beta, senti);
    logits_kernel<<<dim3(32), dim3(64), 0, stream>>>(senti, outW, outb, (float*)d_out);
}

// Round 5
// 6550.182 us; speedup vs baseline: 4.2990x; 4.2990x over previous
//
#include <hip/hip_runtime.h>

// Model: B=32, L1=512, L2=16, D=300, H=300, V=50000, C=3
#define B_  32
#define L1_ 512
#define L2_ 16
#define D_  300
#define H_  300

__device__ __forceinline__ float sigmoid_fast(float x) {
    return 1.0f / (1.0f + __expf(-x));
}
__device__ __forceinline__ float tanh_fast(float x) {
    x = fminf(fmaxf(x, -15.0f), 15.0f);
    float e = __expf(2.0f * x);
    return (e - 1.0f) / (e + 1.0f);
}
// accurate versions for the GRU recurrence (R4 evidence: absmax 0.0 with these)
__device__ __forceinline__ float sigmoid_acc(float x) {
    return 1.0f / (1.0f + expf(-x));
}
__device__ __forceinline__ float wred_sum(float v) {
    #pragma unroll
    for (int off = 32; off > 0; off >>= 1) v += __shfl_xor(v, off);
    return v;
}
__device__ __forceinline__ float wred_max(float v) {
    #pragma unroll
    for (int off = 32; off > 0; off >>= 1) v = fmaxf(v, __shfl_xor(v, off));
    return v;
}

// ---------------- gather rows of emb (row length 300 = 75 float4) ----------------
__global__ __launch_bounds__(256) void gather_kernel(const float* __restrict__ emb,
                                                     const int* __restrict__ ids,
                                                     float* __restrict__ out, int total) {
    for (int i = blockIdx.x * 256 + threadIdx.x; i < total; i += gridDim.x * 256) {
        int row = i / 75, c = i % 75;
        int id = ids[row];
        reinterpret_cast<float4*>(out)[i] =
            reinterpret_cast<const float4*>(emb + (size_t)id * 300)[c];
    }
}

// ---------------- fp32 GEMM: C[M,N] = A[M,K] @ W[N,K]^T (+ bias[n]) ----------------
#define TM 128
#define TN 64
#define TK 16
__global__ __launch_bounds__(256) void gemm_nt(const float* __restrict__ A,
                                               const float* __restrict__ W,
                                               const float* __restrict__ bias,
                                               float* __restrict__ C,
                                               int M, int N, int K) {
    __shared__ __align__(16) float As[TK][TM + 4];
    __shared__ __align__(16) float Bs[TK][TN + 4];
    const int tid = threadIdx.x;
    const int m0 = blockIdx.x * TM;
    const int n0 = blockIdx.y * TN;
    const int tx = tid & 15;
    const int ty = tid >> 4;
    const int lr = tid >> 2;
    const int lk = (tid & 3) << 2;

    float acc[8][4];
    #pragma unroll
    for (int i = 0; i < 8; ++i)
        #pragma unroll
        for (int j = 0; j < 4; ++j) acc[i][j] = 0.f;

    for (int k0 = 0; k0 < K; k0 += TK) {
        const bool kok = (k0 + lk + 3) < K;
        #pragma unroll
        for (int h = 0; h < 2; ++h) {
            float4 v = make_float4(0.f, 0.f, 0.f, 0.f);
            int m = m0 + lr + 64 * h;
            if (kok) v = *reinterpret_cast<const float4*>(&A[(size_t)m * K + k0 + lk]);
            As[lk + 0][lr + 64 * h] = v.x;
            As[lk + 1][lr + 64 * h] = v.y;
            As[lk + 2][lr + 64 * h] = v.z;
            As[lk + 3][lr + 64 * h] = v.w;
        }
        {
            float4 v = make_float4(0.f, 0.f, 0.f, 0.f);
            int n = n0 + lr;
            if (kok && n < N) v = *reinterpret_cast<const float4*>(&W[(size_t)n * K + k0 + lk]);
            Bs[lk + 0][lr] = v.x;
            Bs[lk + 1][lr] = v.y;
            Bs[lk + 2][lr] = v.z;
            Bs[lk + 3][lr] = v.w;
        }
        __syncthreads();
        #pragma unroll
        for (int k = 0; k < TK; ++k) {
            float4 a0 = *reinterpret_cast<const float4*>(&As[k][ty * 8]);
            float4 a1 = *reinterpret_cast<const float4*>(&As[k][ty * 8 + 4]);
            float4 bv = *reinterpret_cast<const float4*>(&Bs[k][tx * 4]);
            float av[8] = {a0.x, a0.y, a0.z, a0.w, a1.x, a1.y, a1.z, a1.w};
            float bb[4] = {bv.x, bv.y, bv.z, bv.w};
            #pragma unroll
            for (int i = 0; i < 8; ++i)
                #pragma unroll
                for (int j = 0; j < 4; ++j) acc[i][j] += av[i] * bb[j];
        }
        __syncthreads();
    }
    #pragma unroll
    for (int i = 0; i < 8; ++i) {
        int m = m0 + ty * 8 + i;
        #pragma unroll
        for (int j = 0; j < 4; ++j) {
            int n = n0 + tx * 4 + j;
            if (n < N) C[(size_t)m * N + n] = acc[i][j] + (bias ? bias[n] : 0.f);
        }
    }
}

// ---------------- attention: scores -> alpha -> context_ -> beta logits ----------------
__global__ __launch_bounds__(256) void attn_kernel(const float* __restrict__ c_proj,
                                                   const float* __restrict__ a_proj,
                                                   const float* __restrict__ asp_emb,
                                                   const float* __restrict__ lin,
                                                   const float* __restrict__ Vatt,
                                                   const float* __restrict__ Vw,
                                                   const float* __restrict__ bVw,
                                                   float* __restrict__ blogit) {
    const int b = blockIdx.y;
    const int chunk = blockIdx.x;
    __shared__ float sA[16 * 300];
    __shared__ float sE[16 * 300];
    __shared__ float sV[300];
    __shared__ float sW[300];
    const int tid = threadIdx.x;
    for (int i = tid; i < 16 * 300; i += 256) {
        sA[i] = a_proj[b * 4800 + i];
        sE[i] = asp_emb[b * 4800 + i];
    }
    for (int i = tid; i < 300; i += 256) {
        sV[i] = Vatt[i];
        sW[i] = Vw[i];
    }
    __syncthreads();
    const int wave = tid >> 6, lane = tid & 63;
    const float bvw = bVw[0];
    for (int li = 0; li < 4; ++li) {
        const int l = chunk * 16 + wave * 4 + li;
        const float* crow = c_proj + (size_t)(b * L1_ + l) * 300;
        float cr[5];
        #pragma unroll
        for (int i = 0; i < 5; ++i) {
            int d = lane + 64 * i;
            cr[i] = (d < 300) ? crow[d] : 0.f;
        }
        float sc[16];
        #pragma unroll
        for (int m = 0; m < 16; ++m) {
            float s = 0.f;
            #pragma unroll
            for (int i = 0; i < 5; ++i) {
                int d = lane + 64 * i;
                if (d < 300) s += tanh_fast(cr[i] + sA[m * 300 + d]) * sV[d];
            }
            s = wred_sum(s);
            sc[m] = s;
        }
        float mx = sc[0];
        #pragma unroll
        for (int m = 1; m < 16; ++m) mx = fmaxf(mx, sc[m]);
        float den = 0.f;
        #pragma unroll
        for (int m = 0; m < 16; ++m) {
            sc[m] = __expf(sc[m] - mx);
            den += sc[m];
        }
        const float inv = 1.f / den;
        const float* lrow = lin + (size_t)(b * L1_ + l) * 300;
        float acc = 0.f;
        #pragma unroll
        for (int i = 0; i < 5; ++i) {
            int d = lane + 64 * i;
            if (d < 300) {
                float cd = 0.f;
                #pragma unroll
                for (int m = 0; m < 16; ++m) cd += sc[m] * sE[m * 300 + d];
                acc += tanh_fast(lrow[d] + cd * inv) * sW[d];
            }
        }
        acc = wred_sum(acc);
        if (lane == 0) blogit[b * L1_ + l] = acc + bvw;
    }
}

// ---------------- beta softmax over L1=512 per batch ----------------
__global__ __launch_bounds__(256) void beta_softmax_kernel(const float* __restrict__ x,
                                                           float* __restrict__ y) {
    const int b = blockIdx.x, tid = threadIdx.x;
    __shared__ float red[4];
    const int wave = tid >> 6, lane = tid & 63;
    float v0 = x[b * 512 + tid];
    float v1 = x[b * 512 + 256 + tid];
    float m = wred_max(fmaxf(v0, v1));
    if (lane == 0) red[wave] = m;
    __syncthreads();
    m = fmaxf(fmaxf(red[0], red[1]), fmaxf(red[2], red[3]));
    float e0 = __expf(v0 - m), e1 = __expf(v1 - m);
    float s = wred_sum(e0 + e1);
    __syncthreads();
    if (lane == 0) red[wave] = s;
    __syncthreads();
    s = red[0] + red[1] + red[2] + red[3];
    const float inv = 1.f / s;
    y[b * 512 + tid] = e0 * inv;
    y[b * 512 + 256 + tid] = e1 * inv;
}

// ---------------- GRU v5: R2's proven agent-scope exchange + asm-pinned weights ----------------
// grid (4,32,2), 256 threads, __launch_bounds__(256,1): 1 wave/SIMD -> VGPR cap
// 512, so the 300 pinned weight floats/thread fit WITHOUT spill (R4 lesson:
// 1024-thread blocks cap at 128 VGPRs -> impossible there).
// Exchange: h via agent-scope atomics in global (R2-proven correct, placement-
// independent); 4-WG monotonic barrier with sticky bounded spin.
__global__ __launch_bounds__(256, 1) void gru5_kernel(const float* __restrict__ xg_f,
                                                      const float* __restrict__ xg_b,
                                                      const float* __restrict__ whh_f,
                                                      const float* __restrict__ whh_b,
                                                      const float* __restrict__ bhh_f,
                                                      const float* __restrict__ bhh_b,
                                                      const float* __restrict__ beta,
                                                      float* __restrict__ hG,   // [64][300]
                                                      int* __restrict__ bar,    // [64]
                                                      float* __restrict__ senti) {
    const int s = blockIdx.x;    // 0..3
    const int b = blockIdx.y;    // 0..31
    const int rev = blockIdx.z;  // 0..1
    const int g = rev * 32 + b;
    const float* xg  = rev ? xg_b : xg_f;
    const float* whh = rev ? whh_b : whh_f;
    const float* bhh = rev ? bhh_b : bhh_f;
    float* hrow = hG + (size_t)g * 300;

    const int tid = threadIdx.x;
    const int e0 = s * 75;
    const bool act = tid < 225;
    const int gate = tid / 75;   // 0=r 1=z 2=n
    const int idx = tid % 75;

    __shared__ __align__(16) float hs[304];
    __shared__ float gg[3][80];

    // ---- weight row -> registers, asm-pinned so the compiler cannot
    // rematerialize the loads inside the step loop (R2 failure mode) ----
    float4 w4[75];
    float bh = 0.f;
    if (act) {
        const int row = gate * 300 + e0 + idx;
        bh = bhh[row];
        const float4* wp = reinterpret_cast<const float4*>(whh + (size_t)row * 300);
        #pragma unroll
        for (int j = 0; j < 75; ++j) w4[j] = wp[j];
    } else {
        #pragma unroll
        for (int j = 0; j < 75; ++j) w4[j] = make_float4(0.f, 0.f, 0.f, 0.f);
    }
    #pragma unroll
    for (int j = 0; j < 75; ++j)
        asm volatile("" : "+v"(w4[j].x), "+v"(w4[j].y), "+v"(w4[j].z), "+v"(w4[j].w));
    asm volatile("" : "+v"(bh));

    for (int i = tid; i < 304; i += 256) hs[i] = 0.f;
    float sacc = 0.f;
    int dead = 0;    // tid 0 only
    int target = 0;
    __syncthreads();

    const float4* hs4 = reinterpret_cast<const float4*>(hs);
    for (int step = 0; step < 512; ++step) {
        const int t = rev ? (511 - step) : step;
        // prefetch xg/beta (independent of h; latency hides under the matvec)
        float xr = 0.f, xz = 0.f, xn = 0.f, bt = 0.f;
        if (tid < 75) {
            const float* xrow = xg + (size_t)(b * 512 + t) * 900;
            const int e = e0 + tid;
            xr = xrow[e];
            xz = xrow[300 + e];
            xn = xrow[600 + e];
            bt = beta[b * 512 + t];
        }
        // matvec from pinned registers, 4 accumulators to break the dep chain
        float a0 = 0.f, a1 = 0.f, a2 = 0.f, a3 = 0.f;
        #pragma unroll
        for (int j = 0; j < 72; j += 4) {
            float4 hv;
            hv = hs4[j];
            a0 = fmaf(w4[j].x, hv.x, a0); a0 = fmaf(w4[j].y, hv.y, a0);
            a0 = fmaf(w4[j].z, hv.z, a0); a0 = fmaf(w4[j].w, hv.w, a0);
            hv = hs4[j + 1];
            a1 = fmaf(w4[j + 1].x, hv.x, a1); a1 = fmaf(w4[j + 1].y, hv.y, a1);
            a1 = fmaf(w4[j + 1].z, hv.z, a1); a1 = fmaf(w4[j + 1].w, hv.w, a1);
            hv = hs4[j + 2];
            a2 = fmaf(w4[j + 2].x, hv.x, a2); a2 = fmaf(w4[j + 2].y, hv.y, a2);
            a2 = fmaf(w4[j + 2].z, hv.z, a2); a2 = fmaf(w4[j + 2].w, hv.w, a2);
            hv = hs4[j + 3];
            a3 = fmaf(w4[j + 3].x, hv.x, a3); a3 = fmaf(w4[j + 3].y, hv.y, a3);
            a3 = fmaf(w4[j + 3].z, hv.z, a3); a3 = fmaf(w4[j + 3].w, hv.w, a3);
        }
        {   // j = 72, 73, 74 tail
            float4 hv;
            hv = hs4[72];
            a0 = fmaf(w4[72].x, hv.x, a0); a0 = fmaf(w4[72].y, hv.y, a0);
            a0 = fmaf(w4[72].z, hv.z, a0); a0 = fmaf(w4[72].w, hv.w, a0);
            hv = hs4[73];
            a1 = fmaf(w4[73].x, hv.x, a1); a1 = fmaf(w4[73].y, hv.y, a1);
            a1 = fmaf(w4[73].z, hv.z, a1); a1 = fmaf(w4[73].w, hv.w, a1);
            hv = hs4[74];
            a2 = fmaf(w4[74].x, hv.x, a2); a2 = fmaf(w4[74].y, hv.y, a2);
            a2 = fmaf(w4[74].z, hv.z, a2); a2 = fmaf(w4[74].w, hv.w, a2);
        }
        const float acc = bh + ((a0 + a1) + (a2 + a3));
        if (act) gg[gate][idx] = acc;
        __syncthreads();
        // gate update for this WG's h slice (accurate exp/tanh: R4 margin)
        if (tid < 75) {
            const int e = e0 + tid;
            const float rr = sigmoid_acc(xr + gg[0][tid]);
            const float zz = sigmoid_acc(xz + gg[1][tid]);
            const float nn = tanhf(xn + rr * gg[2][tid]);
            const float hn = (1.f - zz) * nn + zz * hs[e];
            sacc = fmaf(bt, hn, sacc);
            if (step < 511)
                __hip_atomic_store(&hrow[e], hn, __ATOMIC_RELAXED, __HIP_MEMORY_SCOPE_AGENT);
        }
        if (step == 511) break;
        __syncthreads();  // per-wave vmcnt(0): h stores drained before arrive
        target += 4;
        if (tid == 0) {
            __hip_atomic_fetch_add(&bar[g], 1, __ATOMIC_ACQ_REL, __HIP_MEMORY_SCOPE_AGENT);
            if (!dead) {
                int ok = 0;
                for (int spin = 0; spin < (1 << 16); ++spin) {
                    if (__hip_atomic_load(&bar[g], __ATOMIC_ACQUIRE, __HIP_MEMORY_SCOPE_AGENT) >= target) {
                        ok = 1; break;
                    }
                    __builtin_amdgcn_s_sleep(1);
                }
                if (!ok) dead = 1;  // sticky: never hang the GPU
            }
        }
        __syncthreads();
        // gather fresh full h (agent scope, R2-proven)
        {
            float v0 = __hip_atomic_load(&hrow[tid], __ATOMIC_RELAXED, __HIP_MEMORY_SCOPE_AGENT);
            hs[tid] = v0;
            if (tid < 44)
                hs[256 + tid] = __hip_atomic_load(&hrow[256 + tid], __ATOMIC_RELAXED, __HIP_MEMORY_SCOPE_AGENT);
        }
        __syncthreads();
    }
    if (tid < 75) senti[b * 600 + rev * 300 + e0 + tid] = sacc;
}

// ---------------- final logits: (32,600) x (3,600)^T + outb ----------------
__global__ __launch_bounds__(64) void logits_kernel(const float* __restrict__ senti,
                                                    const float* __restrict__ outW,
                                                    const float* __restrict__ outb,
                                                    float* __restrict__ out) {
    const int b = blockIdx.x, lane = threadIdx.x;
    for (int c = 0; c < 3; ++c) {
        float s = 0.f;
        for (int hh = lane; hh < 600; hh += 64) s += senti[b * 600 + hh] * outW[c * 600 + hh];
        s = wred_sum(s);
        if (lane == 0) out[b * 3 + c] = s + outb[c];
    }
}

extern "C" void kernel_launch(void* const* d_in, const int* in_sizes, int n_in,
                              void* d_out, int out_size, void* d_ws, size_t ws_size,
                              hipStream_t stream) {
    const int* ctx_ids = (const int*)d_in[0];
    const int* asp_ids = (const int*)d_in[1];
    // d_in[2], d_in[3]: masks (all ones, unused by reference)
    const float* emb   = (const float*)d_in[4];
    const float* Wc    = (const float*)d_in[5];
    const float* Wa    = (const float*)d_in[6];
    const float* Vatt  = (const float*)d_in[7];
    const float* Wlin  = (const float*)d_in[8];
    const float* blin  = (const float*)d_in[9];
    const float* Vw    = (const float*)d_in[10];
    const float* bVw   = (const float*)d_in[11];
    const float* wih_f = (const float*)d_in[12];
    const float* whh_f = (const float*)d_in[13];
    const float* bih_f = (const float*)d_in[14];
    const float* bhh_f = (const float*)d_in[15];
    const float* wih_b = (const float*)d_in[16];
    const float* whh_b = (const float*)d_in[17];
    const float* bih_b = (const float*)d_in[18];
    const float* bhh_b = (const float*)d_in[19];
    const float* outW  = (const float*)d_in[20];
    const float* outb  = (const float*)d_in[21];
    float* ws = (float*)d_ws;

    size_t o = 0;
    float* ctx_emb = ws + o; o += (size_t)B_ * L1_ * D_;
    float* asp_emb = ws + o; o += (size_t)B_ * L2_ * D_;
    float* c_proj  = ws + o; o += (size_t)B_ * L1_ * D_;
    float* a_proj  = ws + o; o += (size_t)B_ * L2_ * D_;
    float* lin_buf = ws + o; o += (size_t)B_ * L1_ * D_;
    float* xg_f    = ws + o; o += (size_t)B_ * L1_ * 3 * H_;
    float* xg_b    = ws + o; o += (size_t)B_ * L1_ * 3 * H_;
    float* blogit  = ws + o; o += (size_t)B_ * L1_;
    float* beta    = ws + o; o += (size_t)B_ * L1_;
    float* senti   = ws + o; o += (size_t)B_ * 2 * H_;
    float* hG      = ws + o; o += (size_t)64 * 300;
    int*   bar     = (int*)(ws + o); o += 64;

    hipMemsetAsync(bar, 0, 64 * sizeof(int), stream);

    dim3 blk(256);
    const int tot_ctx = B_ * L1_ * 75;
    const int tot_asp = B_ * L2_ * 75;
    gather_kernel<<<dim3((tot_ctx + 255) / 256), blk, 0, stream>>>(emb, ctx_ids, ctx_emb, tot_ctx);
    gather_kernel<<<dim3((tot_asp + 255) / 256), blk, 0, stream>>>(emb, asp_ids, asp_emb, tot_asp);

    gemm_nt<<<dim3(16384 / 128, 5), blk, 0, stream>>>(ctx_emb, Wc, nullptr, c_proj, 16384, 300, 300);
    gemm_nt<<<dim3(16384 / 128, 5), blk, 0, stream>>>(ctx_emb, Wlin, blin, lin_buf, 16384, 300, 300);
    gemm_nt<<<dim3(512 / 128, 5), blk, 0, stream>>>(asp_emb, Wa, nullptr, a_proj, 512, 300, 300);
    gemm_nt<<<dim3(16384 / 128, 15), blk, 0, stream>>>(ctx_emb, wih_f, bih_f, xg_f, 16384, 900, 300);
    gemm_nt<<<dim3(16384 / 128, 15), blk, 0, stream>>>(ctx_emb, wih_b, bih_b, xg_b, 16384, 900, 300);

    attn_kernel<<<dim3(32, 32), blk, 0, stream>>>(c_proj, a_proj, asp_emb, lin_buf, Vatt, Vw, bVw, blogit);
    beta_softmax_kernel<<<dim3(32), blk, 0, stream>>>(blogit, beta);
    gru5_kernel<<<dim3(4, 32, 2), blk, 0, stream>>>(xg_f, xg_b, whh_f, whh_b, bhh_f, bhh_b,
                                                    beta, hG, bar, senti);
    logits_kernel<<<dim3(32), dim3(64), 0, stream>>>(senti, outW, outb, (float*)d_out);
}

// Round 7
// 2371.876 us; speedup vs baseline: 11.8723x; 2.7616x over previous
//
#include <hip/hip_runtime.h>

// Model: B=32, L1=512, L2=16, D=300, H=300, V=50000, C=3
#define B_  32
#define L1_ 512
#define L2_ 16
#define D_  300
#define H_  300

__device__ __forceinline__ float sigmoid_fast(float x) {
    return 1.0f / (1.0f + __expf(-x));
}
__device__ __forceinline__ float tanh_fast(float x) {
    x = fminf(fmaxf(x, -15.0f), 15.0f);
    float e = __expf(2.0f * x);
    return (e - 1.0f) / (e + 1.0f);
}
// accurate versions for the GRU recurrence (R4/R5 evidence: large margin)
__device__ __forceinline__ float sigmoid_acc(float x) {
    return 1.0f / (1.0f + expf(-x));
}
__device__ __forceinline__ float wred_sum(float v) {
    #pragma unroll
    for (int off = 32; off > 0; off >>= 1) v += __shfl_xor(v, off);
    return v;
}
__device__ __forceinline__ float wred_max(float v) {
    #pragma unroll
    for (int off = 32; off > 0; off >>= 1) v = fmaxf(v, __shfl_xor(v, off));
    return v;
}

// device-coherent (LLC) 8-byte packet ops: sc0 sc1 = bypass L1+L2, no invalidates
__device__ __forceinline__ void store_pkt(long long* p, long long v) {
    asm volatile("global_store_dwordx2 %0, %1, off sc0 sc1" :: "v"(p), "v"(v) : "memory");
}
__device__ __forceinline__ long long load_pkt(const long long* p) {
    long long v;
    asm volatile("global_load_dwordx2 %0, %1, off sc0 sc1\n\t"
                 "s_waitcnt vmcnt(0)"
                 : "=v"(v) : "v"(p) : "memory");
    return v;
}

// ---------------- gather rows of emb (row length 300 = 75 float4) ----------------
__global__ __launch_bounds__(256) void gather_kernel(const float* __restrict__ emb,
                                                     const int* __restrict__ ids,
                                                     float* __restrict__ out, int total) {
    for (int i = blockIdx.x * 256 + threadIdx.x; i < total; i += gridDim.x * 256) {
        int row = i / 75, c = i % 75;
        int id = ids[row];
        reinterpret_cast<float4*>(out)[i] =
            reinterpret_cast<const float4*>(emb + (size_t)id * 300)[c];
    }
}

// ---------------- fp32 GEMM: C[M,N] = A[M,K] @ W[N,K]^T (+ bias[n]) ----------------
#define TM 128
#define TN 64
#define TK 16
__global__ __launch_bounds__(256) void gemm_nt(const float* __restrict__ A,
                                               const float* __restrict__ W,
                                               const float* __restrict__ bias,
                                               float* __restrict__ C,
                                               int M, int N, int K) {
    __shared__ __align__(16) float As[TK][TM + 4];
    __shared__ __align__(16) float Bs[TK][TN + 4];
    const int tid = threadIdx.x;
    const int m0 = blockIdx.x * TM;
    const int n0 = blockIdx.y * TN;
    const int tx = tid & 15;
    const int ty = tid >> 4;
    const int lr = tid >> 2;
    const int lk = (tid & 3) << 2;

    float acc[8][4];
    #pragma unroll
    for (int i = 0; i < 8; ++i)
        #pragma unroll
        for (int j = 0; j < 4; ++j) acc[i][j] = 0.f;

    for (int k0 = 0; k0 < K; k0 += TK) {
        const bool kok = (k0 + lk + 3) < K;
        #pragma unroll
        for (int h = 0; h < 2; ++h) {
            float4 v = make_float4(0.f, 0.f, 0.f, 0.f);
            int m = m0 + lr + 64 * h;
            if (kok) v = *reinterpret_cast<const float4*>(&A[(size_t)m * K + k0 + lk]);
            As[lk + 0][lr + 64 * h] = v.x;
            As[lk + 1][lr + 64 * h] = v.y;
            As[lk + 2][lr + 64 * h] = v.z;
            As[lk + 3][lr + 64 * h] = v.w;
        }
        {
            float4 v = make_float4(0.f, 0.f, 0.f, 0.f);
            int n = n0 + lr;
            if (kok && n < N) v = *reinterpret_cast<const float4*>(&W[(size_t)n * K + k0 + lk]);
            Bs[lk + 0][lr] = v.x;
            Bs[lk + 1][lr] = v.y;
            Bs[lk + 2][lr] = v.z;
            Bs[lk + 3][lr] = v.w;
        }
        __syncthreads();
        #pragma unroll
        for (int k = 0; k < TK; ++k) {
            float4 a0 = *reinterpret_cast<const float4*>(&As[k][ty * 8]);
            float4 a1 = *reinterpret_cast<const float4*>(&As[k][ty * 8 + 4]);
            float4 bv = *reinterpret_cast<const float4*>(&Bs[k][tx * 4]);
            float av[8] = {a0.x, a0.y, a0.z, a0.w, a1.x, a1.y, a1.z, a1.w};
            float bb[4] = {bv.x, bv.y, bv.z, bv.w};
            #pragma unroll
            for (int i = 0; i < 8; ++i)
                #pragma unroll
                for (int j = 0; j < 4; ++j) acc[i][j] += av[i] * bb[j];
        }
        __syncthreads();
    }
    #pragma unroll
    for (int i = 0; i < 8; ++i) {
        int m = m0 + ty * 8 + i;
        #pragma unroll
        for (int j = 0; j < 4; ++j) {
            int n = n0 + tx * 4 + j;
            if (n < N) C[(size_t)m * N + n] = acc[i][j] + (bias ? bias[n] : 0.f);
        }
    }
}

// ---------------- attention: scores -> alpha -> context_ -> beta logits ----------------
__global__ __launch_bounds__(256) void attn_kernel(const float* __restrict__ c_proj,
                                                   const float* __restrict__ a_proj,
                                                   const float* __restrict__ asp_emb,
                                                   const float* __restrict__ lin,
                                                   const float* __restrict__ Vatt,
                                                   const float* __restrict__ Vw,
                                                   const float* __restrict__ bVw,
                                                   float* __restrict__ blogit) {
    const int b = blockIdx.y;
    const int chunk = blockIdx.x;
    __shared__ float sA[16 * 300];
    __shared__ float sE[16 * 300];
    __shared__ float sV[300];
    __shared__ float sW[300];
    const int tid = threadIdx.x;
    for (int i = tid; i < 16 * 300; i += 256) {
        sA[i] = a_proj[b * 4800 + i];
        sE[i] = asp_emb[b * 4800 + i];
    }
    for (int i = tid; i < 300; i += 256) {
        sV[i] = Vatt[i];
        sW[i] = Vw[i];
    }
    __syncthreads();
    const int wave = tid >> 6, lane = tid & 63;
    const float bvw = bVw[0];
    for (int li = 0; li < 4; ++li) {
        const int l = chunk * 16 + wave * 4 + li;
        const float* crow = c_proj + (size_t)(b * L1_ + l) * 300;
        float cr[5];
        #pragma unroll
        for (int i = 0; i < 5; ++i) {
            int d = lane + 64 * i;
            cr[i] = (d < 300) ? crow[d] : 0.f;
        }
        float sc[16];
        #pragma unroll
        for (int m = 0; m < 16; ++m) {
            float s = 0.f;
            #pragma unroll
            for (int i = 0; i < 5; ++i) {
                int d = lane + 64 * i;
                if (d < 300) s += tanh_fast(cr[i] + sA[m * 300 + d]) * sV[d];
            }
            s = wred_sum(s);
            sc[m] = s;
        }
        float mx = sc[0];
        #pragma unroll
        for (int m = 1; m < 16; ++m) mx = fmaxf(mx, sc[m]);
        float den = 0.f;
        #pragma unroll
        for (int m = 0; m < 16; ++m) {
            sc[m] = __expf(sc[m] - mx);
            den += sc[m];
        }
        const float inv = 1.f / den;
        const float* lrow = lin + (size_t)(b * L1_ + l) * 300;
        float acc = 0.f;
        #pragma unroll
        for (int i = 0; i < 5; ++i) {
            int d = lane + 64 * i;
            if (d < 300) {
                float cd = 0.f;
                #pragma unroll
                for (int m = 0; m < 16; ++m) cd += sc[m] * sE[m * 300 + d];
                acc += tanh_fast(lrow[d] + cd * inv) * sW[d];
            }
        }
        acc = wred_sum(acc);
        if (lane == 0) blogit[b * L1_ + l] = acc + bvw;
    }
}

// ---------------- beta softmax over L1=512 per batch ----------------
__global__ __launch_bounds__(256) void beta_softmax_kernel(const float* __restrict__ x,
                                                           float* __restrict__ y) {
    const int b = blockIdx.x, tid = threadIdx.x;
    __shared__ float red[4];
    const int wave = tid >> 6, lane = tid & 63;
    float v0 = x[b * 512 + tid];
    float v1 = x[b * 512 + 256 + tid];
    float m = wred_max(fmaxf(v0, v1));
    if (lane == 0) red[wave] = m;
    __syncthreads();
    m = fmaxf(fmaxf(red[0], red[1]), fmaxf(red[2], red[3]));
    float e0 = __expf(v0 - m), e1 = __expf(v1 - m);
    float s = wred_sum(e0 + e1);
    __syncthreads();
    if (lane == 0) red[wave] = s;
    __syncthreads();
    s = red[0] + red[1] + red[2] + red[3];
    const float inv = 1.f / s;
    y[b * 512 + tid] = e0 * inv;
    y[b * 512 + 256 + tid] = e1 * inv;
}

// ---------------- GRU v7: pinned register weights + tag-carried dataflow exchange ----------------
// grid (4,32,2), 256 threads, 1 block/CU (co-resident: 256 blocks = 256 CUs).
// NO barrier, NO atomics: each h element is published as an 8B packet
// {f32 value, i32 step} with a device-coherent sc0 sc1 store; readers issue
// tagged loads and retry until tag==step. The tag travels in the same aligned
// 8B transaction -> no fence needed, placement-independent (LLC-coherent).
// Slots are double-buffered by step parity; overwrite of a parity slot (step
// t+2) can only happen after every reader consumed step t (dataflow-proven).
// Slot area memset to 0xFF each launch (tag -1 != any step).
__global__ __launch_bounds__(256, 1) void gru7_kernel(const float* __restrict__ xg_f,
                                                      const float* __restrict__ xg_b,
                                                      const float* __restrict__ whh_f,
                                                      const float* __restrict__ whh_b,
                                                      const float* __restrict__ bhh_f,
                                                      const float* __restrict__ bhh_b,
                                                      const float* __restrict__ beta,
                                                      long long* __restrict__ slot, // [2][64][4][80]
                                                      float* __restrict__ senti) {
    const int s = blockIdx.x;    // slice 0..3 (owns h [75s, 75s+75))
    const int b = blockIdx.y;    // 0..31
    const int rev = blockIdx.z;  // 0..1
    const int g = rev * 32 + b;
    const float* xg  = rev ? xg_b : xg_f;
    const float* whh = rev ? whh_b : whh_f;
    const float* bhh = rev ? bhh_b : bhh_f;

    const int tid = threadIdx.x;
    const int e0 = s * 75;
    const bool act = tid < 225;
    const int gate = tid / 75;   // 0=r 1=z 2=n
    const int idx = tid % 75;

    __shared__ __align__(16) float hs[304];
    __shared__ float gg[3][80];

    // ---- weight row -> registers, asm-pinned (R5-proven residency) ----
    float4 w4[75];
    float bh = 0.f;
    if (act) {
        const int row = gate * 300 + e0 + idx;
        bh = bhh[row];
        const float4* wp = reinterpret_cast<const float4*>(whh + (size_t)row * 300);
        #pragma unroll
        for (int j = 0; j < 75; ++j) w4[j] = wp[j];
    } else {
        #pragma unroll
        for (int j = 0; j < 75; ++j) w4[j] = make_float4(0.f, 0.f, 0.f, 0.f);
    }
    #pragma unroll
    for (int j = 0; j < 75; ++j)
        asm volatile("" : "+v"(w4[j].x), "+v"(w4[j].y), "+v"(w4[j].z), "+v"(w4[j].w));
    asm volatile("" : "+v"(bh));

    // reader setup: tid<225 owns one foreign element
    int fsl = 0, fli = 0;
    const long long* rp0 = nullptr;
    if (tid < 225) {
        fsl = tid / 75;
        if (fsl >= s) ++fsl;           // skip own slice
        fli = tid % 75;
    }
    long long* wp0 = slot + ((size_t)g * 4 + s) * 80 + tid;            // parity 0 base (writer)
    const long long* rbase = slot + ((size_t)g * 4 + fsl) * 80 + fli;  // parity 0 base (reader)

    for (int i = tid; i < 304; i += 256) hs[i] = 0.f;
    float sacc = 0.f;
    int gaveup = 0;
    __syncthreads();

    const float4* hs4 = reinterpret_cast<const float4*>(hs);
    for (int step = 0; step < 512; ++step) {
        const int t = rev ? (511 - step) : step;
        // prefetch xg/beta (independent of h; latency hides under the matvec)
        float xr = 0.f, xz = 0.f, xn = 0.f, bt = 0.f;
        if (tid < 75) {
            const float* xrow = xg + (size_t)(b * 512 + t) * 900;
            const int e = e0 + tid;
            xr = xrow[e];
            xz = xrow[300 + e];
            xn = xrow[600 + e];
            bt = beta[b * 512 + t];
        }
        // matvec from pinned registers, 4 accumulators (identical order to R5)
        float a0 = 0.f, a1 = 0.f, a2 = 0.f, a3 = 0.f;
        #pragma unroll
        for (int j = 0; j < 72; j += 4) {
            float4 hv;
            hv = hs4[j];
            a0 = fmaf(w4[j].x, hv.x, a0); a0 = fmaf(w4[j].y, hv.y, a0);
            a0 = fmaf(w4[j].z, hv.z, a0); a0 = fmaf(w4[j].w, hv.w, a0);
            hv = hs4[j + 1];
            a1 = fmaf(w4[j + 1].x, hv.x, a1); a1 = fmaf(w4[j + 1].y, hv.y, a1);
            a1 = fmaf(w4[j + 1].z, hv.z, a1); a1 = fmaf(w4[j + 1].w, hv.w, a1);
            hv = hs4[j + 2];
            a2 = fmaf(w4[j + 2].x, hv.x, a2); a2 = fmaf(w4[j + 2].y, hv.y, a2);
            a2 = fmaf(w4[j + 2].z, hv.z, a2); a2 = fmaf(w4[j + 2].w, hv.w, a2);
            hv = hs4[j + 3];
            a3 = fmaf(w4[j + 3].x, hv.x, a3); a3 = fmaf(w4[j + 3].y, hv.y, a3);
            a3 = fmaf(w4[j + 3].z, hv.z, a3); a3 = fmaf(w4[j + 3].w, hv.w, a3);
        }
        {   // j = 72, 73, 74 tail
            float4 hv;
            hv = hs4[72];
            a0 = fmaf(w4[72].x, hv.x, a0); a0 = fmaf(w4[72].y, hv.y, a0);
            a0 = fmaf(w4[72].z, hv.z, a0); a0 = fmaf(w4[72].w, hv.w, a0);
            hv = hs4[73];
            a1 = fmaf(w4[73].x, hv.x, a1); a1 = fmaf(w4[73].y, hv.y, a1);
            a1 = fmaf(w4[73].z, hv.z, a1); a1 = fmaf(w4[73].w, hv.w, a1);
            hv = hs4[74];
            a2 = fmaf(w4[74].x, hv.x, a2); a2 = fmaf(w4[74].y, hv.y, a2);
            a2 = fmaf(w4[74].z, hv.z, a2); a2 = fmaf(w4[74].w, hv.w, a2);
        }
        const float acc = bh + ((a0 + a1) + (a2 + a3));
        if (act) gg[gate][idx] = acc;
        __syncthreads();
        // own-slice gate update; publish packet {h, step} (no fence needed)
        if (tid < 75) {
            const int e = e0 + tid;
            const float rr = sigmoid_acc(xr + gg[0][tid]);
            const float zz = sigmoid_acc(xz + gg[1][tid]);
            const float nn = tanhf(xn + rr * gg[2][tid]);
            const float hn = (1.f - zz) * nn + zz * hs[e];
            sacc = fmaf(bt, hn, sacc);
            hs[e] = hn;
            if (step < 511) {
                long long pkt = ((long long)(unsigned)step << 32) |
                                (unsigned)__float_as_int(hn);
                store_pkt(wp0 + (size_t)(step & 1) * 64 * 4 * 80, pkt);
            }
        }
        if (step == 511) break;
        // tagged gather of the 3 foreign slices (disjoint hs region vs writer)
        if (tid < 225) {
            const long long* p = rbase + (size_t)(step & 1) * 64 * 4 * 80;
            long long v = 0;
            if (!gaveup) {
                int ok = 0;
                for (int it = 0; it < (1 << 16); ++it) {
                    v = load_pkt(p);
                    if (((int)(v >> 32)) == step) { ok = 1; break; }
                }
                if (!ok) gaveup = 1;   // sticky: never hang; keep last value
            } else {
                v = load_pkt(p);
            }
            hs[fsl * 75 + fli] = __int_as_float((int)(v & 0xffffffffLL));
        }
        __syncthreads();
    }
    if (tid < 75) senti[b * 600 + rev * 300 + e0 + tid] = sacc;
}

// ---------------- final logits: (32,600) x (3,600)^T + outb ----------------
__global__ __launch_bounds__(64) void logits_kernel(const float* __restrict__ senti,
                                                    const float* __restrict__ outW,
                                                    const float* __restrict__ outb,
                                                    float* __restrict__ out) {
    const int b = blockIdx.x, lane = threadIdx.x;
    for (int c = 0; c < 3; ++c) {
        float s = 0.f;
        for (int hh = lane; hh < 600; hh += 64) s += senti[b * 600 + hh] * outW[c * 600 + hh];
        s = wred_sum(s);
        if (lane == 0) out[b * 3 + c] = s + outb[c];
    }
}

extern "C" void kernel_launch(void* const* d_in, const int* in_sizes, int n_in,
                              void* d_out, int out_size, void* d_ws, size_t ws_size,
                              hipStream_t stream) {
    const int* ctx_ids = (const int*)d_in[0];
    const int* asp_ids = (const int*)d_in[1];
    // d_in[2], d_in[3]: masks (all ones, unused by reference)
    const float* emb   = (const float*)d_in[4];
    const float* Wc    = (const float*)d_in[5];
    const float* Wa    = (const float*)d_in[6];
    const float* Vatt  = (const float*)d_in[7];
    const float* Wlin  = (const float*)d_in[8];
    const float* blin  = (const float*)d_in[9];
    const float* Vw    = (const float*)d_in[10];
    const float* bVw   = (const float*)d_in[11];
    const float* wih_f = (const float*)d_in[12];
    const float* whh_f = (const float*)d_in[13];
    const float* bih_f = (const float*)d_in[14];
    const float* bhh_f = (const float*)d_in[15];
    const float* wih_b = (const float*)d_in[16];
    const float* whh_b = (const float*)d_in[17];
    const float* bih_b = (const float*)d_in[18];
    const float* bhh_b = (const float*)d_in[19];
    const float* outW  = (const float*)d_in[20];
    const float* outb  = (const float*)d_in[21];
    float* ws = (float*)d_ws;

    size_t o = 0;
    float* ctx_emb = ws + o; o += (size_t)B_ * L1_ * D_;
    float* asp_emb = ws + o; o += (size_t)B_ * L2_ * D_;
    float* c_proj  = ws + o; o += (size_t)B_ * L1_ * D_;
    float* a_proj  = ws + o; o += (size_t)B_ * L2_ * D_;
    float* lin_buf = ws + o; o += (size_t)B_ * L1_ * D_;
    float* xg_f    = ws + o; o += (size_t)B_ * L1_ * 3 * H_;
    float* xg_b    = ws + o; o += (size_t)B_ * L1_ * 3 * H_;
    float* blogit  = ws + o; o += (size_t)B_ * L1_;
    float* beta    = ws + o; o += (size_t)B_ * L1_;
    float* senti   = ws + o; o += (size_t)B_ * 2 * H_;
    o = (o + 1) & ~(size_t)1;                 // 8B-align the slot area
    long long* slot = (long long*)(ws + o);   // [2][64][4][80] packets
    const size_t slot_ll = (size_t)2 * 64 * 4 * 80;
    o += slot_ll * 2;

    hipMemsetAsync(slot, 0xFF, slot_ll * sizeof(long long), stream);

    dim3 blk(256);
    const int tot_ctx = B_ * L1_ * 75;
    const int tot_asp = B_ * L2_ * 75;
    gather_kernel<<<dim3((tot_ctx + 255) / 256), blk, 0, stream>>>(emb, ctx_ids, ctx_emb, tot_ctx);
    gather_kernel<<<dim3((tot_asp + 255) / 256), blk, 0, stream>>>(emb, asp_ids, asp_emb, tot_asp);

    gemm_nt<<<dim3(16384 / 128, 5), blk, 0, stream>>>(ctx_emb, Wc, nullptr, c_proj, 16384, 300, 300);
    gemm_nt<<<dim3(16384 / 128, 5), blk, 0, stream>>>(ctx_emb, Wlin, blin, lin_buf, 16384, 300, 300);
    gemm_nt<<<dim3(512 / 128, 5), blk, 0, stream>>>(asp_emb, Wa, nullptr, a_proj, 512, 300, 300);
    gemm_nt<<<dim3(16384 / 128, 15), blk, 0, stream>>>(ctx_emb, wih_f, bih_f, xg_f, 16384, 900, 300);
    gemm_nt<<<dim3(16384 / 128, 15), blk, 0, stream>>>(ctx_emb, wih_b, bih_b, xg_b, 16384, 900, 300);

    attn_kernel<<<dim3(32, 32), blk, 0, stream>>>(c_proj, a_proj, asp_emb, lin_buf, Vatt, Vw, bVw, blogit);
    beta_softmax_kernel<<<dim3(32), blk, 0, stream>>>(blogit, beta);
    gru7_kernel<<<dim3(4, 32, 2), blk, 0, stream>>>(xg_f, xg_b, whh_f, whh_b, bhh_f, bhh_b,
                                                    beta, slot, senti);
    logits_kernel<<<dim3(32), dim3(64), 0, stream>>>(senti, outW, outb, (float*)d_out);
}